// Round 1
// baseline (360.519 us; speedup 1.0000x reference)
//
#include <hip/hip_runtime.h>
#include <hip/hip_bf16.h>

// MultiHeadedAttention: B=4, T=2048, F=1024, h=16, dk=64.
// Pipeline: f32->bf16 converts -> 3 proj GEMMs -> V transpose -> flash attn -> out GEMM.

typedef unsigned short u16;
typedef __attribute__((ext_vector_type(8))) short short8;
typedef __attribute__((ext_vector_type(4))) float f32x4;

#define GLOAD16(g, l) __builtin_amdgcn_global_load_lds( \
    (const __attribute__((address_space(1))) unsigned int*)(g), \
    (__attribute__((address_space(3))) unsigned int*)(l), 16, 0, 0)

__device__ __forceinline__ u16 f2bf(float x) {
  unsigned int u = __float_as_uint(x);
  return (u16)((u + 0x7fffu + ((u >> 16) & 1u)) >> 16);  // RNE, finite inputs
}

// ---------------- f32 -> bf16 convert ----------------
__global__ __launch_bounds__(256) void cvt_bf16(const float* __restrict__ in,
                                                u16* __restrict__ out, int n4) {
  int i = blockIdx.x * 256 + threadIdx.x;
  if (i >= n4) return;
  float4 v = ((const float4*)in)[i];
  ushort4 o;
  o.x = f2bf(v.x); o.y = f2bf(v.y); o.z = f2bf(v.z); o.w = f2bf(v.w);
  ((ushort4*)out)[i] = o;
}

// ---------------- GEMM: C[M,N] = A[M,K] * B[N,K]^T + bias ----------------
// M=8192, N=K=1024. 128x128 tile, BK=64, 256 threads (4 waves, 2x2).
// LDS XOR-swizzle byte ^= ((row&7)<<4), applied via pre-swizzled global source.
// EPI 0: bf16 out scattered to [B,h,T,dk].  EPI 1: f32 out [M,N].
template <int EPI>
__global__ __launch_bounds__(256) void gemm_bt(const u16* __restrict__ A,
                                               const u16* __restrict__ Bw,
                                               const float* __restrict__ bias,
                                               void* __restrict__ Cout) {
  __shared__ u16 As[128 * 64];
  __shared__ u16 Bs[128 * 64];
  const int t = threadIdx.x;
  const int lane = t & 63;
  const int w = t >> 6;
  const int wm = w >> 1, wn = w & 1;
  const int l15 = lane & 15, l4 = lane >> 4;

  // XCD-aware swizzle: 512 blocks, 8 XCDs, 64 per XCD (bijective: 512 % 8 == 0)
  const int bid = blockIdx.x;
  const int swz = (bid & 7) * 64 + (bid >> 3);
  const int brow = swz >> 3;  // 64 M-tiles
  const int bcol = swz & 7;   // 8 N-tiles

  f32x4 acc[4][4] = {};

  const int srow = t >> 3;          // 0..31
  const int sbyte = (t & 7) * 16;   // 0..112

  for (int kt = 0; kt < 16; ++kt) {
    const int k0 = kt * 64;
    __syncthreads();
#pragma unroll
    for (int i = 0; i < 4; ++i) {
      const int r = i * 32 + srow;
      const int sb = sbyte ^ ((r & 7) << 4);
      GLOAD16((const char*)(A + (size_t)(brow * 128 + r) * 1024 + k0) + sb,
              &As[(i * 4096 + t * 16) >> 1]);
      GLOAD16((const char*)(Bw + (size_t)(bcol * 128 + r) * 1024 + k0) + sb,
              &Bs[(i * 4096 + t * 16) >> 1]);
    }
    __syncthreads();
#pragma unroll
    for (int kf = 0; kf < 2; ++kf) {
      short8 af[4], bfv[4];
#pragma unroll
      for (int mi = 0; mi < 4; ++mi) {
        const int r = wm * 64 + mi * 16 + l15;
        const int byt = r * 128 + ((kf * 64 + l4 * 16) ^ ((r & 7) << 4));
        af[mi] = *(const short8*)&As[byt >> 1];
      }
#pragma unroll
      for (int ni = 0; ni < 4; ++ni) {
        const int r = wn * 64 + ni * 16 + l15;
        const int byt = r * 128 + ((kf * 64 + l4 * 16) ^ ((r & 7) << 4));
        bfv[ni] = *(const short8*)&Bs[byt >> 1];
      }
#pragma unroll
      for (int mi = 0; mi < 4; ++mi)
#pragma unroll
        for (int ni = 0; ni < 4; ++ni)
          acc[mi][ni] = __builtin_amdgcn_mfma_f32_16x16x32_bf16(
              af[mi], bfv[ni], acc[mi][ni], 0, 0, 0);
    }
  }

#pragma unroll
  for (int ni = 0; ni < 4; ++ni) {
    const int n = bcol * 128 + wn * 64 + ni * 16 + l15;
    const float bn = bias[n];
#pragma unroll
    for (int mi = 0; mi < 4; ++mi) {
      const int mb = brow * 128 + wm * 64 + mi * 16 + l4 * 4;
#pragma unroll
      for (int r = 0; r < 4; ++r) {
        const float v = acc[mi][ni][r] + bn;
        const int m = mb + r;
        if (EPI == 0) {
          // [B,h,T,dk]: b=m>>11, tok=m&2047, h=n>>6, d=n&63
          const int b_ = m >> 11, tok = m & 2047, h_ = n >> 6, d = n & 63;
          ((u16*)Cout)[(((size_t)(b_ * 16 + h_) * 2048 + tok) << 6) + d] = f2bf(v);
        } else {
          ((float*)Cout)[(size_t)m * 1024 + n] = v;
        }
      }
    }
  }
}

// ---------------- V transpose: [B,h,T,dk] -> [B,h,dk,T] ----------------
__global__ __launch_bounds__(256) void transpose_v(const u16* __restrict__ Vp,
                                                   u16* __restrict__ Vt) {
  const int bh = blockIdx.x >> 5;            // 64 heads
  const int t0 = (blockIdx.x & 31) * 64;     // 32 t-tiles of 64
  __shared__ u16 tile[64][65];
  const u16* src = Vp + (size_t)bh * 2048 * 64;
  u16* dst = Vt + (size_t)bh * 64 * 2048;
  const int c = threadIdx.x & 63;
  const int r0 = threadIdx.x >> 6;  // 0..3
#pragma unroll
  for (int j = 0; j < 16; ++j) {
    const int r = r0 + j * 4;
    tile[r][c] = src[(size_t)(t0 + r) * 64 + c];
  }
  __syncthreads();
#pragma unroll
  for (int j = 0; j < 16; ++j) {
    const int d = r0 + j * 4;
    dst[(size_t)d * 2048 + t0 + c] = tile[c][d];
  }
}

// ---------------- Flash attention ----------------
// Grid: 64 heads * 16 q-tiles = 1024 blocks, 256 threads (4 waves x 32 Q-rows).
// Q [B,h,T,dk] bf16, K [B,h,T,dk] bf16, Vt [B,h,dk,T] bf16 -> ctx [B,T,F] bf16.
__global__ __launch_bounds__(256) void attn_fwd(const u16* __restrict__ Q,
                                                const u16* __restrict__ Kp,
                                                const u16* __restrict__ Vt,
                                                const int* __restrict__ mask,
                                                u16* __restrict__ ctx) {
  __shared__ u16 Ks[64 * 64];
  __shared__ u16 Vs[64 * 64];
  __shared__ u16 Ps[4][32 * 64];

  const int t = threadIdx.x, lane = t & 63, w = t >> 6;
  const int l15 = lane & 15, l4 = lane >> 4;

  // XCD swizzle so the 16 q-tiles of a head co-locate per XCD (1024 % 8 == 0)
  const int bid = blockIdx.x;
  const int swz = (bid & 7) * 128 + (bid >> 3);
  const int bh = swz >> 4;                 // 0..63
  const int b_ = bh >> 4, h_ = bh & 15;
  const int q0 = (swz & 15) * 128 + w * 32;

  const size_t headO = (size_t)bh * 2048 * 64;

  // Q fragments in registers (2 row-frags x 2 k-frags)
  short8 qf[2][2];
#pragma unroll
  for (int mi = 0; mi < 2; ++mi)
#pragma unroll
    for (int kf = 0; kf < 2; ++kf) {
      const int row = q0 + mi * 16 + l15;
      qf[mi][kf] = *(const short8*)(Q + headO + (size_t)row * 64 + kf * 32 + l4 * 8);
    }

  f32x4 oacc[2][4] = {};
  float m_run[2][4], l_run[2][4];
#pragma unroll
  for (int mi = 0; mi < 2; ++mi)
#pragma unroll
    for (int r = 0; r < 4; ++r) { m_run[mi][r] = -1e30f; l_run[mi][r] = 0.f; }

  const int srow = t >> 3;
  const int sbyte = (t & 7) * 16;
  const float scale = 0.125f;  // 1/sqrt(64)

  for (int kt = 0; kt < 32; ++kt) {
    const int kb = kt * 64;
    __syncthreads();
#pragma unroll
    for (int i = 0; i < 2; ++i) {
      const int r = i * 32 + srow;
      const int sb = sbyte ^ ((r & 7) << 4);
      GLOAD16((const char*)(Kp + headO + (size_t)(kb + r) * 64) + sb,
              &Ks[(i * 4096 + t * 16) >> 1]);
      GLOAD16((const char*)(Vt + (size_t)bh * 131072 + (size_t)r * 2048 + kb) + sb,
              &Vs[(i * 4096 + t * 16) >> 1]);
    }
    __syncthreads();

    int mk[4];
#pragma unroll
    for (int ni = 0; ni < 4; ++ni) mk[ni] = mask[b_ * 2048 + kb + ni * 16 + l15];

    // S = Q K^T  (rows = q, cols = keys)
    f32x4 sa[2][4] = {};
#pragma unroll
    for (int kf = 0; kf < 2; ++kf) {
      short8 kfr[4];
#pragma unroll
      for (int ni = 0; ni < 4; ++ni) {
        const int r = ni * 16 + l15;
        kfr[ni] = *(const short8*)&Ks[(r * 128 + ((kf * 64 + l4 * 16) ^ ((r & 7) << 4))) >> 1];
      }
#pragma unroll
      for (int mi = 0; mi < 2; ++mi)
#pragma unroll
        for (int ni = 0; ni < 4; ++ni)
          sa[mi][ni] = __builtin_amdgcn_mfma_f32_16x16x32_bf16(
              qf[mi][kf], kfr[ni], sa[mi][ni], 0, 0, 0);
    }

    // online softmax; write P (bf16) to per-wave swizzled LDS
#pragma unroll
    for (int mi = 0; mi < 2; ++mi) {
#pragma unroll
      for (int r = 0; r < 4; ++r) {
        float sv[4];
#pragma unroll
        for (int ni = 0; ni < 4; ++ni)
          sv[ni] = (mk[ni] == 0) ? -3e38f : sa[mi][ni][r] * scale;
        float mt = fmaxf(fmaxf(sv[0], sv[1]), fmaxf(sv[2], sv[3]));
#pragma unroll
        for (int off = 1; off < 16; off <<= 1) mt = fmaxf(mt, __shfl_xor(mt, off));
        const float mnew = fmaxf(m_run[mi][r], mt);
        const float corr = __expf(m_run[mi][r] - mnew);
        m_run[mi][r] = mnew;
        float rs = 0.f;
        u16 pu[4];
#pragma unroll
        for (int ni = 0; ni < 4; ++ni) {
          const float p = __expf(sv[ni] - mnew);
          rs += p;
          pu[ni] = f2bf(p);
        }
#pragma unroll
        for (int off = 1; off < 16; off <<= 1) rs += __shfl_xor(rs, off);
        l_run[mi][r] = l_run[mi][r] * corr + rs;
#pragma unroll
        for (int ni = 0; ni < 4; ++ni) oacc[mi][ni][r] *= corr;
        const int prow = mi * 16 + l4 * 4 + r;
#pragma unroll
        for (int ni = 0; ni < 4; ++ni) {
          const int pb = prow * 128 + (((ni * 16 + l15) * 2) ^ ((prow & 7) << 4));
          Ps[w][pb >> 1] = pu[ni];
        }
      }
    }

    // O += P * V   (A = P from wave-private LDS, B = Vt rows)
#pragma unroll
    for (int kf = 0; kf < 2; ++kf) {
      short8 pa[2], vb[4];
#pragma unroll
      for (int mi = 0; mi < 2; ++mi) {
        const int r = mi * 16 + l15;
        pa[mi] = *(const short8*)&Ps[w][(r * 128 + ((kf * 64 + l4 * 16) ^ ((r & 7) << 4))) >> 1];
      }
#pragma unroll
      for (int ni = 0; ni < 4; ++ni) {
        const int r = ni * 16 + l15;
        vb[ni] = *(const short8*)&Vs[(r * 128 + ((kf * 64 + l4 * 16) ^ ((r & 7) << 4))) >> 1];
      }
#pragma unroll
      for (int mi = 0; mi < 2; ++mi)
#pragma unroll
        for (int ni = 0; ni < 4; ++ni)
          oacc[mi][ni] = __builtin_amdgcn_mfma_f32_16x16x32_bf16(
              pa[mi], vb[ni], oacc[mi][ni], 0, 0, 0);
    }
  }

  // normalize + store ctx[B,T,F] (concat heads along features)
#pragma unroll
  for (int mi = 0; mi < 2; ++mi) {
#pragma unroll
    for (int r = 0; r < 4; ++r) {
      const float inv = l_run[mi][r] > 0.f ? 1.f / l_run[mi][r] : 0.f;
      const int tok = q0 + mi * 16 + l4 * 4 + r;
#pragma unroll
      for (int ni = 0; ni < 4; ++ni) {
        const float v = oacc[mi][ni][r] * inv;
        ctx[((size_t)b_ * 2048 + tok) * 1024 + h_ * 64 + ni * 16 + l15] = f2bf(v);
      }
    }
  }
}

// ---------------- host launcher ----------------
extern "C" void kernel_launch(void* const* d_in, const int* in_sizes, int n_in,
                              void* d_out, int out_size, void* d_ws, size_t ws_size,
                              hipStream_t stream) {
  const float* q_in = (const float*)d_in[0];
  const float* k_in = (const float*)d_in[1];
  const float* v_in = (const float*)d_in[2];
  const int*   mask = (const int*)d_in[3];
  const float* Wq = (const float*)d_in[4];
  const float* bq = (const float*)d_in[5];
  const float* Wk = (const float*)d_in[6];
  const float* bk = (const float*)d_in[7];
  const float* Wv = (const float*)d_in[8];
  const float* bv = (const float*)d_in[9];
  const float* Wo = (const float*)d_in[10];
  const float* bo = (const float*)d_in[11];
  float* out = (float*)d_out;

  char* ws = (char*)d_ws;
  const size_t BTF = (size_t)8192 * 1024;  // 8,388,608 elements
  u16* xq = (u16*)(ws);                        // bf16 query  [B,T,F]
  u16* xk = (u16*)(ws + 16777216);             // bf16 key
  u16* xv = (u16*)(ws + 33554432);             // bf16 value
  u16* Qp = (u16*)(ws + 50331648);             // [B,h,T,dk]
  u16* Kp = (u16*)(ws + 67108864);
  u16* Vp = (u16*)(ws + 83886080);
  u16* wqb = (u16*)(ws + 100663296);           // bf16 weights, 2 MiB each
  u16* wkb = (u16*)(ws + 102760448);
  u16* wvb = (u16*)(ws + 104857600);
  u16* wob = (u16*)(ws + 106954752);
  // reuse dead regions:
  u16* Vtb = xq;   // [B,h,dk,T] (query bf16 dead after Q projection)
  u16* ctx = xk;   // [B,T,F]    (key bf16 dead after K projection)

  // converts
  cvt_bf16<<<8192, 256, 0, stream>>>(q_in, xq, (int)(BTF / 4));
  cvt_bf16<<<8192, 256, 0, stream>>>(k_in, xk, (int)(BTF / 4));
  cvt_bf16<<<8192, 256, 0, stream>>>(v_in, xv, (int)(BTF / 4));
  cvt_bf16<<<1024, 256, 0, stream>>>(Wq, wqb, 262144);
  cvt_bf16<<<1024, 256, 0, stream>>>(Wk, wkb, 262144);
  cvt_bf16<<<1024, 256, 0, stream>>>(Wv, wvb, 262144);
  cvt_bf16<<<1024, 256, 0, stream>>>(Wo, wob, 262144);

  // projections
  gemm_bt<0><<<512, 256, 0, stream>>>(xq, wqb, bq, Qp);
  gemm_bt<0><<<512, 256, 0, stream>>>(xk, wkb, bk, Kp);
  gemm_bt<0><<<512, 256, 0, stream>>>(xv, wvb, bv, Vp);

  // V transpose to [B,h,dk,T]
  transpose_v<<<2048, 256, 0, stream>>>(Vp, Vtb);

  // flash attention -> ctx [B,T,F] bf16
  attn_fwd<<<1024, 256, 0, stream>>>(Qp, Kp, Vtb, mask, ctx);

  // output projection (f32 out)
  gemm_bt<1><<<512, 256, 0, stream>>>(ctx, wob, bo, out);
}